// Round 1
// baseline (275.976 us; speedup 1.0000x reference)
//
#include <hip/hip_runtime.h>
#include <math.h>

#define BATCH 8
#define HH 192
#define WW 192
#define BIGF 1e10f

__device__ __forceinline__ float sigmoidf_(float x) {
    return 1.0f / (1.0f + expf(-x));
}

__device__ __forceinline__ float waveReduceAdd(float v) {
    #pragma unroll
    for (int o = 32; o > 0; o >>= 1) v += __shfl_down(v, o, 64);
    return v;
}

// Kernel 1: per-row 1D EDT (squared distance to nearest fg / bg column in the row)
__global__ void rowEdtKernel(const int* __restrict__ tgt,
                             float* __restrict__ colmin_fg,
                             float* __restrict__ colmin_bg,
                             int* __restrict__ flags) {
    const int blk = blockIdx.x;          // b*HH + r
    const int b = blk / HH, r = blk % HH;
    const int x = threadIdx.x;           // 0..191
    __shared__ int fg[WW];
    const int t = tgt[(b * HH + r) * WW + x];
    fg[x] = (t > 0) ? 1 : 0;
    __syncthreads();
    int dfg = 0x7fffffff, dbg = 0x7fffffff;
    #pragma unroll 4
    for (int xp = 0; xp < WW; ++xp) {
        const int d = (x - xp) * (x - xp);
        if (fg[xp]) { dfg = min(dfg, d); } else { dbg = min(dbg, d); }
    }
    colmin_fg[(b * HH + r) * WW + x] = (dfg == 0x7fffffff) ? BIGF : (float)dfg;
    colmin_bg[(b * HH + r) * WW + x] = (dbg == 0x7fffffff) ? BIGF : (float)dbg;
    if (x == 0) {
        // thread 0's distance is finite iff the row contains any fg (resp. bg)
        if (dfg != 0x7fffffff) atomicOr(&flags[b], 1);
        if (dbg != 0x7fffffff) atomicOr(&flags[BATCH + b], 1);
    }
}

// Kernel 2: column lower-envelope -> signed distance phi; fused BCE + focal + boundary
__global__ void envelopeLossKernel(const float* __restrict__ pred,
                                   const int* __restrict__ tgt,
                                   const float* __restrict__ colmin_fg,
                                   const float* __restrict__ colmin_bg,
                                   const int* __restrict__ flags,
                                   double* __restrict__ acc) {
    const int blk = blockIdx.x;          // b*HH + y
    const int b = blk / HH, y = blk % HH;
    const int x = threadIdx.x;           // 0..191

    const float* cf = colmin_fg + (size_t)b * HH * WW + x;
    const float* cb = colmin_bg + (size_t)b * HH * WW + x;
    float d2o = BIGF, d2i = BIGF;
    #pragma unroll 4
    for (int rp = 0; rp < HH; ++rp) {
        const float dy = (float)((y - rp) * (y - rp));
        d2o = fminf(d2o, cf[rp * WW] + dy);
        d2i = fminf(d2i, cb[rp * WW] + dy);
    }
    const float maxd2 = (float)((HH - 1) * (HH - 1) + (WW - 1) * (WW - 1));
    const float maxd = sqrtf(maxd2);
    const float dist_out = flags[b]         ? sqrtf(fminf(d2o, maxd2)) : maxd;
    const float dist_in  = flags[BATCH + b] ? sqrtf(fminf(d2i, maxd2)) : maxd;

    const int t = tgt[(b * HH + y) * WW + x];
    const float tf = (float)t;
    const bool isfg = (t > 0);
    const float phi = isfg ? -dist_in : dist_out;

    const float p = sigmoidf_(pred[(b * HH + y) * WW + x]);

    // boundary
    const float wgt = expf(-fabsf(phi) * 0.1f);
    const float bnd = wgt * fabsf(phi * p);

    // bce (log clamped at -100 like torch BCELoss)
    const float logp   = fmaxf(logf(p), -100.0f);
    const float log1mp = fmaxf(logf(1.0f - p), -100.0f);
    const float bce = -(tf * logp + (1.0f - tf) * log1mp);

    // focal
    const float pc = fminf(fmaxf(p, 1e-6f), 1.0f - 1e-6f);
    const float pt = pc * tf + (1.0f - pc) * (1.0f - tf);
    const float at = 0.25f * tf + 0.75f * (1.0f - tf);
    const float om = 1.0f - pt;
    const float focal = -at * om * om * logf(pt);

    const float sb = waveReduceAdd(bce);
    const float sf = waveReduceAdd(focal);
    const float sd = waveReduceAdd(bnd);
    if ((threadIdx.x & 63) == 0) {
        atomicAdd(&acc[0], (double)sb);
        atomicAdd(&acc[1], (double)sf);
        atomicAdd(&acc[2], (double)sd);
    }
}

// Kernel 3: SSIM, separable 11-tap gaussian (valid), fused mean
__global__ void ssimKernel(const float* __restrict__ pred,
                           const int* __restrict__ tgt,
                           double* __restrict__ acc) {
    const int OW = WW - 10, OH = HH - 10;
    const int blk = blockIdx.x;          // b*OH + yo
    const int b = blk / OH, yo = blk % OH;
    const int x = threadIdx.x;           // 0..191

    // 11-tap gaussian, sigma=1.5, normalized (matches numpy fp32 to ~1e-7)
    float g[11];
    {
        float s = 0.0f;
        #pragma unroll
        for (int k = 0; k < 11; ++k) {
            const float d = (float)(k - 5);
            g[k] = expf(-d * d / 4.5f);
            s += g[k];
        }
        const float inv = 1.0f / s;
        #pragma unroll
        for (int k = 0; k < 11; ++k) g[k] *= inv;
    }

    __shared__ float sp[WW], st[WW], spp[WW], stt[WW], spt[WW];
    float ap = 0, at = 0, app = 0, att = 0, apt = 0;
    #pragma unroll
    for (int k = 0; k < 11; ++k) {
        const int row = yo + k;
        const float p = sigmoidf_(pred[(b * HH + row) * WW + x]);
        const float t = (float)tgt[(b * HH + row) * WW + x];
        const float gk = g[k];
        ap += gk * p; at += gk * t;
        app += gk * p * p; att += gk * t * t; apt += gk * p * t;
    }
    sp[x] = ap; st[x] = at; spp[x] = app; stt[x] = att; spt[x] = apt;
    __syncthreads();

    float term = 0.0f;
    if (x < OW) {
        float mx = 0, my = 0, mxx = 0, myy = 0, mxy = 0;
        #pragma unroll
        for (int k = 0; k < 11; ++k) {
            mx += g[k] * sp[x + k];  my += g[k] * st[x + k];
            mxx += g[k] * spp[x + k]; myy += g[k] * stt[x + k];
            mxy += g[k] * spt[x + k];
        }
        const float C1 = 1e-4f, C2 = 9e-4f;
        const float sx = mxx - mx * mx, sy = myy - my * my, sxy = mxy - mx * my;
        const float num = (2.0f * mx * my + C1) * (2.0f * sxy + C2);
        const float den = (mx * mx + my * my + C1) * (sx + sy + C2);
        term = num / den;
    }
    const float s = waveReduceAdd(term);
    if ((threadIdx.x & 63) == 0) atomicAdd(&acc[3], (double)s);
}

// Kernel 4: combine into the scalar output
__global__ void combineKernel(const double* __restrict__ acc, float* __restrict__ out) {
    const double N1 = (double)(BATCH * HH * WW);
    const double N2 = (double)(BATCH * (HH - 10) * (WW - 10));
    out[0] = (float)((acc[0] + acc[1] + acc[2]) / N1 + acc[3] / N2);
}

extern "C" void kernel_launch(void* const* d_in, const int* in_sizes, int n_in,
                              void* d_out, int out_size, void* d_ws, size_t ws_size,
                              hipStream_t stream) {
    const float* pred = (const float*)d_in[0];
    const int* tgt = (const int*)d_in[1];

    double* acc = (double*)d_ws;                         // 4 doubles
    int* flags = (int*)((char*)d_ws + 32);               // 16 ints
    float* colmin_fg = (float*)((char*)d_ws + 128);
    float* colmin_bg = colmin_fg + (size_t)BATCH * HH * WW;

    hipMemsetAsync(d_ws, 0, 128, stream);

    rowEdtKernel<<<BATCH * HH, WW, 0, stream>>>(tgt, colmin_fg, colmin_bg, flags);
    envelopeLossKernel<<<BATCH * HH, WW, 0, stream>>>(pred, tgt, colmin_fg, colmin_bg, flags, acc);
    ssimKernel<<<BATCH * (HH - 10), WW, 0, stream>>>(pred, tgt, acc);
    combineKernel<<<1, 1, 0, stream>>>(acc, (float*)d_out);
}

// Round 2
// 118.166 us; speedup vs baseline: 2.3355x; 2.3355x over previous
//
#include <hip/hip_runtime.h>
#include <math.h>

#define BATCH 8
#define HH 192
#define WW 192
#define BIGF 1e10f

__device__ __forceinline__ float sigmoidf_(float x) {
    return 1.0f / (1.0f + expf(-x));
}

__device__ __forceinline__ float waveReduceAdd(float v) {
    #pragma unroll
    for (int o = 32; o > 0; o >>= 1) v += __shfl_down(v, o, 64);
    return v;
}

// Kernel 1: per-row 1D EDT, branchless float4; writes colmin TRANSPOSED [b][x][r]
__global__ void rowEdtKernel(const int* __restrict__ tgt,
                             float* __restrict__ colminT_fg,
                             float* __restrict__ colminT_bg,
                             int* __restrict__ flags) {
    const int blk = blockIdx.x;          // b*HH + r
    const int b = blk / HH, r = blk % HH;
    const int x = threadIdx.x;           // 0..191
    __shared__ float cf[WW], cb[WW];
    const int t = tgt[(b * HH + r) * WW + x];
    const bool fg = (t > 0);
    cf[x] = fg ? 0.0f : BIGF;
    cb[x] = fg ? BIGF : 0.0f;
    __syncthreads();

    float dfg = BIGF, dbg = BIGF;
    const float fx = (float)x;
    #pragma unroll 8
    for (int xp = 0; xp < WW; xp += 4) {
        const float4 vf = *(const float4*)&cf[xp];
        const float4 vb = *(const float4*)&cb[xp];
        const float e0 = fx - (float)xp,       s0 = e0 * e0;
        const float e1 = fx - (float)(xp + 1), s1 = e1 * e1;
        const float e2 = fx - (float)(xp + 2), s2 = e2 * e2;
        const float e3 = fx - (float)(xp + 3), s3 = e3 * e3;
        dfg = fminf(dfg, fminf(fminf(s0 + vf.x, s1 + vf.y), fminf(s2 + vf.z, s3 + vf.w)));
        dbg = fminf(dbg, fminf(fminf(s0 + vb.x, s1 + vb.y), fminf(s2 + vb.z, s3 + vb.w)));
    }
    colminT_fg[((size_t)b * WW + x) * HH + r] = dfg;
    colminT_bg[((size_t)b * WW + x) * HH + r] = dbg;
    if (x == 0) {
        if (dfg < 1e9f) atomicOr(&flags[b], 1);         // row has fg
        if (dbg < 1e9f) atomicOr(&flags[BATCH + b], 1); // row has bg
    }
}

// Kernel 2: one block per (b, column x). Column envelope from LDS, fused losses.
__global__ void envelopeLossKernel(const float* __restrict__ pred,
                                   const int* __restrict__ tgt,
                                   const float* __restrict__ colminT_fg,
                                   const float* __restrict__ colminT_bg,
                                   const int* __restrict__ flags,
                                   double* __restrict__ acc) {
    const int blk = blockIdx.x;          // b*WW + x
    const int b = blk / WW, x = blk % WW;
    const int y = threadIdx.x;           // 0..191

    __shared__ float scf[HH], scb[HH];
    scf[y] = colminT_fg[((size_t)b * WW + x) * HH + y];
    scb[y] = colminT_bg[((size_t)b * WW + x) * HH + y];
    __syncthreads();

    float d2o = BIGF, d2i = BIGF;
    const float fy = (float)y;
    #pragma unroll 8
    for (int rp = 0; rp < HH; rp += 4) {
        const float4 vf = *(const float4*)&scf[rp];
        const float4 vb = *(const float4*)&scb[rp];
        const float e0 = fy - (float)rp,       s0 = e0 * e0;
        const float e1 = fy - (float)(rp + 1), s1 = e1 * e1;
        const float e2 = fy - (float)(rp + 2), s2 = e2 * e2;
        const float e3 = fy - (float)(rp + 3), s3 = e3 * e3;
        d2o = fminf(d2o, fminf(fminf(s0 + vf.x, s1 + vf.y), fminf(s2 + vf.z, s3 + vf.w)));
        d2i = fminf(d2i, fminf(fminf(s0 + vb.x, s1 + vb.y), fminf(s2 + vb.z, s3 + vb.w)));
    }

    const float maxd2 = (float)((HH - 1) * (HH - 1) + (WW - 1) * (WW - 1));
    const float maxd = sqrtf(maxd2);
    const float dist_out = flags[b]         ? sqrtf(fminf(d2o, maxd2)) : maxd;
    const float dist_in  = flags[BATCH + b] ? sqrtf(fminf(d2i, maxd2)) : maxd;

    const int t = tgt[(b * HH + y) * WW + x];
    const float tf = (float)t;
    const float phi = (t > 0) ? -dist_in : dist_out;

    const float p = sigmoidf_(pred[(b * HH + y) * WW + x]);

    // boundary
    const float wgt = expf(-fabsf(phi) * 0.1f);
    const float bnd = wgt * fabsf(phi * p);

    // bce (log clamped at -100 like torch BCELoss)
    const float logp   = fmaxf(logf(p), -100.0f);
    const float log1mp = fmaxf(logf(1.0f - p), -100.0f);
    const float bce = -(tf * logp + (1.0f - tf) * log1mp);

    // focal
    const float pc = fminf(fmaxf(p, 1e-6f), 1.0f - 1e-6f);
    const float pt = pc * tf + (1.0f - pc) * (1.0f - tf);
    const float at = 0.25f * tf + 0.75f * (1.0f - tf);
    const float om = 1.0f - pt;
    const float focal = -at * om * om * logf(pt);

    // block reduce (3 waves) -> 1 atomic per counter per block
    __shared__ float red[3][3];
    const float sb = waveReduceAdd(bce);
    const float sf = waveReduceAdd(focal);
    const float sd = waveReduceAdd(bnd);
    const int wid = threadIdx.x >> 6;
    if ((threadIdx.x & 63) == 0) { red[wid][0] = sb; red[wid][1] = sf; red[wid][2] = sd; }
    __syncthreads();
    if (threadIdx.x == 0) {
        atomicAdd(&acc[0], (double)(red[0][0] + red[1][0] + red[2][0]));
        atomicAdd(&acc[1], (double)(red[0][1] + red[1][1] + red[2][1]));
        atomicAdd(&acc[2], (double)(red[0][2] + red[1][2] + red[2][2]));
    }
}

// Kernel 3: SSIM, separable 11-tap gaussian (valid), fused mean
__global__ void ssimKernel(const float* __restrict__ pred,
                           const int* __restrict__ tgt,
                           double* __restrict__ acc) {
    const int OW = WW - 10, OH = HH - 10;
    const int blk = blockIdx.x;          // b*OH + yo
    const int b = blk / OH, yo = blk % OH;
    const int x = threadIdx.x;           // 0..191

    float g[11];
    {
        float s = 0.0f;
        #pragma unroll
        for (int k = 0; k < 11; ++k) {
            const float d = (float)(k - 5);
            g[k] = expf(-d * d / 4.5f);
            s += g[k];
        }
        const float inv = 1.0f / s;
        #pragma unroll
        for (int k = 0; k < 11; ++k) g[k] *= inv;
    }

    __shared__ float sp[WW], st[WW], spp[WW], stt[WW], spt[WW];
    float ap = 0, at = 0, app = 0, att = 0, apt = 0;
    #pragma unroll
    for (int k = 0; k < 11; ++k) {
        const int row = yo + k;
        const float p = sigmoidf_(pred[(b * HH + row) * WW + x]);
        const float t = (float)tgt[(b * HH + row) * WW + x];
        const float gk = g[k];
        ap += gk * p; at += gk * t;
        app += gk * p * p; att += gk * t * t; apt += gk * p * t;
    }
    sp[x] = ap; st[x] = at; spp[x] = app; stt[x] = att; spt[x] = apt;
    __syncthreads();

    float term = 0.0f;
    if (x < OW) {
        float mx = 0, my = 0, mxx = 0, myy = 0, mxy = 0;
        #pragma unroll
        for (int k = 0; k < 11; ++k) {
            mx += g[k] * sp[x + k];  my += g[k] * st[x + k];
            mxx += g[k] * spp[x + k]; myy += g[k] * stt[x + k];
            mxy += g[k] * spt[x + k];
        }
        const float C1 = 1e-4f, C2 = 9e-4f;
        const float sx = mxx - mx * mx, sy = myy - my * my, sxy = mxy - mx * my;
        const float num = (2.0f * mx * my + C1) * (2.0f * sxy + C2);
        const float den = (mx * mx + my * my + C1) * (sx + sy + C2);
        term = num / den;
    }
    __shared__ float red[3];
    const float s = waveReduceAdd(term);
    const int wid = threadIdx.x >> 6;
    if ((threadIdx.x & 63) == 0) red[wid] = s;
    __syncthreads();
    if (threadIdx.x == 0) atomicAdd(&acc[3], (double)(red[0] + red[1] + red[2]));
}

// Kernel 4: combine into the scalar output
__global__ void combineKernel(const double* __restrict__ acc, float* __restrict__ out) {
    const double N1 = (double)(BATCH * HH * WW);
    const double N2 = (double)(BATCH * (HH - 10) * (WW - 10));
    out[0] = (float)((acc[0] + acc[1] + acc[2]) / N1 + acc[3] / N2);
}

extern "C" void kernel_launch(void* const* d_in, const int* in_sizes, int n_in,
                              void* d_out, int out_size, void* d_ws, size_t ws_size,
                              hipStream_t stream) {
    const float* pred = (const float*)d_in[0];
    const int* tgt = (const int*)d_in[1];

    double* acc = (double*)d_ws;                         // 4 doubles
    int* flags = (int*)((char*)d_ws + 32);               // 16 ints
    float* colminT_fg = (float*)((char*)d_ws + 128);
    float* colminT_bg = colminT_fg + (size_t)BATCH * HH * WW;

    hipMemsetAsync(d_ws, 0, 128, stream);

    rowEdtKernel<<<BATCH * HH, WW, 0, stream>>>(tgt, colminT_fg, colminT_bg, flags);
    envelopeLossKernel<<<BATCH * WW, HH, 0, stream>>>(pred, tgt, colminT_fg, colminT_bg, flags, acc);
    ssimKernel<<<BATCH * (HH - 10), WW, 0, stream>>>(pred, tgt, acc);
    combineKernel<<<1, 1, 0, stream>>>(acc, (float*)d_out);
}

// Round 3
// 36.058 us; speedup vs baseline: 7.6537x; 3.2771x over previous
//
#include <hip/hip_runtime.h>
#include <math.h>

#define BATCH 8
#define HH 192
#define WW 192
#define BIGF 1e10f
#define NROWBLK (BATCH * HH)   // 1536 row-EDT blocks
#define OH (HH - 10)           // 182
#define OW (WW - 10)           // 182
#define NSSIMBLK (BATCH * OH)  // 1456 ssim blocks
#define NENVBLK (BATCH * WW)   // 1536 envelope blocks

__device__ __forceinline__ float waveReduceAdd(float v) {
    #pragma unroll
    for (int o = 32; o > 0; o >>= 1) v += __shfl_down(v, o, 64);
    return v;
}

// Kernel 1 (fused): blocks [0,NROWBLK) do per-row 1D EDT (write colminT float2{fg,bg},
// transposed [b][x][r]); blocks [NROWBLK, NROWBLK+NSSIMBLK) do one SSIM output row each,
// writing a per-block partial sum (no atomics).
__global__ void prepKernel(const float* __restrict__ pred,
                           const int* __restrict__ tgt,
                           float2* __restrict__ colminT,
                           int* __restrict__ flags,
                           float* __restrict__ ssimPart) {
    __shared__ __align__(16) float smem[5 * WW];

    if (blockIdx.x < NROWBLK) {
        // ---- row EDT ----
        const int b = blockIdx.x / HH, r = blockIdx.x % HH;
        const int x = threadIdx.x;  // 0..191
        float* cf = smem;
        float* cb = smem + WW;
        const int t = tgt[(b * HH + r) * WW + x];
        const bool fg = (t > 0);
        cf[x] = fg ? 0.0f : BIGF;
        cb[x] = fg ? BIGF : 0.0f;
        __syncthreads();

        float a0 = BIGF, a1 = BIGF, a2 = BIGF, a3 = BIGF;
        float c0 = BIGF, c1 = BIGF, c2 = BIGF, c3 = BIGF;
        const float fx = (float)x;
        #pragma unroll 6
        for (int xp = 0; xp < WW; xp += 4) {
            const float4 vf = *(const float4*)&cf[xp];
            const float4 vb = *(const float4*)&cb[xp];
            const float e0 = fx - (float)xp;
            const float e1 = fx - (float)(xp + 1);
            const float e2 = fx - (float)(xp + 2);
            const float e3 = fx - (float)(xp + 3);
            a0 = fminf(a0, fmaf(e0, e0, vf.x)); a1 = fminf(a1, fmaf(e1, e1, vf.y));
            a2 = fminf(a2, fmaf(e2, e2, vf.z)); a3 = fminf(a3, fmaf(e3, e3, vf.w));
            c0 = fminf(c0, fmaf(e0, e0, vb.x)); c1 = fminf(c1, fmaf(e1, e1, vb.y));
            c2 = fminf(c2, fmaf(e2, e2, vb.z)); c3 = fminf(c3, fmaf(e3, e3, vb.w));
        }
        const float dfg = fminf(fminf(a0, a1), fminf(a2, a3));
        const float dbg = fminf(fminf(c0, c1), fminf(c2, c3));
        colminT[((size_t)b * WW + x) * HH + r] = make_float2(dfg, dbg);
        if (x == 0) {
            if (dfg < 1e9f) flags[b] = 1;          // benign race: all writers store 1
            if (dbg < 1e9f) flags[BATCH + b] = 1;
        }
    } else {
        // ---- SSIM (separable 11-tap gaussian, valid) ----
        const int blk = blockIdx.x - NROWBLK;
        const int b = blk / OH, yo = blk % OH;
        const int x = threadIdx.x;  // 0..191

        float g[11];
        {
            float s = 0.0f;
            #pragma unroll
            for (int k = 0; k < 11; ++k) {
                const float d = (float)(k - 5);
                g[k] = __expf(-d * d / 4.5f);
                s += g[k];
            }
            const float inv = 1.0f / s;
            #pragma unroll
            for (int k = 0; k < 11; ++k) g[k] *= inv;
        }

        float* sp = smem;
        float* st = smem + WW;
        float* spp = smem + 2 * WW;
        float* stt = smem + 3 * WW;
        float* spt = smem + 4 * WW;

        float ap = 0, at = 0, app = 0, att = 0, apt = 0;
        #pragma unroll
        for (int k = 0; k < 11; ++k) {
            const int row = yo + k;
            const float z = pred[(b * HH + row) * WW + x];
            const float p = 1.0f / (1.0f + __expf(-z));
            const float t = (float)tgt[(b * HH + row) * WW + x];
            const float gk = g[k];
            ap += gk * p; at += gk * t;
            app += gk * p * p; att += gk * t * t; apt += gk * p * t;
        }
        sp[x] = ap; st[x] = at; spp[x] = app; stt[x] = att; spt[x] = apt;
        __syncthreads();

        float term = 0.0f;
        if (x < OW) {
            float mx = 0, my = 0, mxx = 0, myy = 0, mxy = 0;
            #pragma unroll
            for (int k = 0; k < 11; ++k) {
                mx += g[k] * sp[x + k];  my += g[k] * st[x + k];
                mxx += g[k] * spp[x + k]; myy += g[k] * stt[x + k];
                mxy += g[k] * spt[x + k];
            }
            const float C1 = 1e-4f, C2 = 9e-4f;
            const float sx = mxx - mx * mx, sy = myy - my * my, sxy = mxy - mx * my;
            const float num = (2.0f * mx * my + C1) * (2.0f * sxy + C2);
            const float den = (mx * mx + my * my + C1) * (sx + sy + C2);
            term = num / den;
        }
        __shared__ float red[3];
        const float s = waveReduceAdd(term);
        const int wid = threadIdx.x >> 6;
        if ((threadIdx.x & 63) == 0) red[wid] = s;
        __syncthreads();
        if (threadIdx.x == 0) ssimPart[blk] = red[0] + red[1] + red[2];
    }
}

// Kernel 2: one block per (b, column x). Column envelope from LDS, fused per-pixel
// losses, per-block partial sums (no atomics).
__global__ void envelopeLossKernel(const float* __restrict__ pred,
                                   const int* __restrict__ tgt,
                                   const float2* __restrict__ colminT,
                                   const int* __restrict__ flags,
                                   float4* __restrict__ envPart) {
    const int b = blockIdx.x / WW, x = blockIdx.x % WW;
    const int y = threadIdx.x;  // 0..191

    __shared__ __align__(16) float2 scfb[HH];
    scfb[y] = colminT[((size_t)b * WW + x) * HH + y];
    __syncthreads();

    float o0 = BIGF, o1 = BIGF, o2 = BIGF, o3 = BIGF;
    float i0 = BIGF, i1 = BIGF, i2 = BIGF, i3 = BIGF;
    const float fy = (float)y;
    #pragma unroll 6
    for (int rp = 0; rp < HH; rp += 4) {
        const float4 v0 = *(const float4*)&scfb[rp];       // {fg_r, bg_r, fg_r+1, bg_r+1}
        const float4 v1 = *(const float4*)&scfb[rp + 2];
        const float e0 = fy - (float)rp;
        const float e1 = fy - (float)(rp + 1);
        const float e2 = fy - (float)(rp + 2);
        const float e3 = fy - (float)(rp + 3);
        o0 = fminf(o0, fmaf(e0, e0, v0.x)); i0 = fminf(i0, fmaf(e0, e0, v0.y));
        o1 = fminf(o1, fmaf(e1, e1, v0.z)); i1 = fminf(i1, fmaf(e1, e1, v0.w));
        o2 = fminf(o2, fmaf(e2, e2, v1.x)); i2 = fminf(i2, fmaf(e2, e2, v1.y));
        o3 = fminf(o3, fmaf(e3, e3, v1.z)); i3 = fminf(i3, fmaf(e3, e3, v1.w));
    }
    const float d2o = fminf(fminf(o0, o1), fminf(o2, o3));
    const float d2i = fminf(fminf(i0, i1), fminf(i2, i3));

    const float maxd2 = (float)((HH - 1) * (HH - 1) + (WW - 1) * (WW - 1));
    const float maxd = sqrtf(maxd2);
    const float dist_out = flags[b]         ? sqrtf(fminf(d2o, maxd2)) : maxd;
    const float dist_in  = flags[BATCH + b] ? sqrtf(fminf(d2i, maxd2)) : maxd;

    const int t = tgt[(b * HH + y) * WW + x];
    const float tf = (float)t;
    const float phi = (t > 0) ? -dist_in : dist_out;

    const float z = pred[(b * HH + y) * WW + x];
    const float p = 1.0f / (1.0f + __expf(-z));

    // boundary
    const float wgt = __expf(-fabsf(phi) * 0.1f);
    const float bnd = wgt * fabsf(phi * p);

    // bce (log clamped at -100 like torch BCELoss)
    const float logp   = fmaxf(__logf(p), -100.0f);
    const float log1mp = fmaxf(__logf(1.0f - p), -100.0f);
    const float bce = -(tf * logp + (1.0f - tf) * log1mp);

    // focal
    const float pc = fminf(fmaxf(p, 1e-6f), 1.0f - 1e-6f);
    const float pt = pc * tf + (1.0f - pc) * (1.0f - tf);
    const float at = 0.25f * tf + 0.75f * (1.0f - tf);
    const float om = 1.0f - pt;
    const float focal = -at * om * om * __logf(pt);

    // block reduce -> one float4 store per block
    __shared__ float red[3][3];
    const float sb = waveReduceAdd(bce);
    const float sf = waveReduceAdd(focal);
    const float sd = waveReduceAdd(bnd);
    const int wid = threadIdx.x >> 6;
    if ((threadIdx.x & 63) == 0) { red[wid][0] = sb; red[wid][1] = sf; red[wid][2] = sd; }
    __syncthreads();
    if (threadIdx.x == 0) {
        envPart[blockIdx.x] = make_float4(red[0][0] + red[1][0] + red[2][0],
                                          red[0][1] + red[1][1] + red[2][1],
                                          red[0][2] + red[1][2] + red[2][2], 0.0f);
    }
}

// Kernel 3: final reduction + combine
__global__ void reduceKernel(const float4* __restrict__ envPart,
                             const float* __restrict__ ssimPart,
                             float* __restrict__ out) {
    const int tid = threadIdx.x;  // 256
    float s0 = 0, s1 = 0, s2 = 0, s3 = 0;
    for (int i = tid; i < NENVBLK; i += 256) {
        const float4 v = envPart[i];
        s0 += v.x; s1 += v.y; s2 += v.z;
    }
    for (int i = tid; i < NSSIMBLK; i += 256) s3 += ssimPart[i];
    s0 = waveReduceAdd(s0); s1 = waveReduceAdd(s1);
    s2 = waveReduceAdd(s2); s3 = waveReduceAdd(s3);
    __shared__ float red[4][4];
    const int wid = tid >> 6;
    if ((tid & 63) == 0) { red[wid][0] = s0; red[wid][1] = s1; red[wid][2] = s2; red[wid][3] = s3; }
    __syncthreads();
    if (tid == 0) {
        float t0 = 0, t1 = 0, t2 = 0, t3 = 0;
        #pragma unroll
        for (int w = 0; w < 4; ++w) { t0 += red[w][0]; t1 += red[w][1]; t2 += red[w][2]; t3 += red[w][3]; }
        const float N1 = (float)(BATCH * HH * WW);
        const float N2 = (float)(BATCH * OH * OW);
        out[0] = (t0 + t1 + t2) / N1 + t3 / N2;
    }
}

extern "C" void kernel_launch(void* const* d_in, const int* in_sizes, int n_in,
                              void* d_out, int out_size, void* d_ws, size_t ws_size,
                              hipStream_t stream) {
    const float* pred = (const float*)d_in[0];
    const int* tgt = (const int*)d_in[1];

    int* flags = (int*)d_ws;                                        // 64 B
    float4* envPart = (float4*)((char*)d_ws + 64);                  // 1536*16 = 24576 B
    float* ssimPart = (float*)((char*)d_ws + 64 + 24576);           // 1456*4  = 5824 B
    float2* colminT = (float2*)((char*)d_ws + 30720);               // 8*192*192*8 = 2359296 B

    hipMemsetAsync(d_ws, 0, 64, stream);

    prepKernel<<<NROWBLK + NSSIMBLK, WW, 0, stream>>>(pred, tgt, colminT, flags, ssimPart);
    envelopeLossKernel<<<NENVBLK, HH, 0, stream>>>(pred, tgt, colminT, flags, envPart);
    reduceKernel<<<1, 256, 0, stream>>>(envPart, ssimPart, (float*)d_out);
}